// Round 3
// baseline (2203.478 us; speedup 1.0000x reference)
//
#include <hip/hip_runtime.h>

#define NN 100000
#define NE 5000000
#define NB 16
#define NLAYER 4

#define RPB 256                    // rows per bucket (== 1<<8)
#define NBUCKET ((NN + RPB - 1) / RPB)   // 391
#define CHUNK 4096                 // edges per binning block

// h[n*16+b] = x[n*16+b] * tw[ct[n]] + tb[ct[n]]
__global__ void type_affine(const float* __restrict__ x,
                            const float* __restrict__ tw,
                            const float* __restrict__ tb,
                            const int* __restrict__ ct,
                            float* __restrict__ h) {
    int idx = blockIdx.x * blockDim.x + threadIdx.x;
    if (idx >= NN * NB) return;
    int n = idx >> 4;
    int t = ct[n];
    h[idx] = x[idx] * tw[t] + tb[t];
}

// per-chunk LDS histogram of coarse buckets -> global bucket counts
__global__ void bucket_count(const int* __restrict__ rows, int* __restrict__ gcnt) {
    __shared__ int hist[NBUCKET];
    for (int t = threadIdx.x; t < NBUCKET; t += 256) hist[t] = 0;
    __syncthreads();
    int base = blockIdx.x * CHUNK;
    int n = min(CHUNK, NE - base);
    for (int k = threadIdx.x; k < n; k += 256)
        atomicAdd(&hist[rows[base + k] >> 8], 1);
    __syncthreads();
    for (int t = threadIdx.x; t < NBUCKET; t += 256)
        if (hist[t] > 0) atomicAdd(&gcnt[t], hist[t]);
}

// single-block exclusive scan of 391 bucket counts -> bbase (NBUCKET+1), cursor copy
__global__ void bucket_scan(const int* __restrict__ gcnt,
                            int* __restrict__ bbase, int* __restrict__ gcursor) {
    __shared__ int s[512];
    int t = threadIdx.x;
    int v = (t < NBUCKET) ? gcnt[t] : 0;
    s[t] = v;
    __syncthreads();
    for (int off = 1; off < 512; off <<= 1) {
        int u = (t >= off) ? s[t - off] : 0;
        __syncthreads();
        s[t] += u;
        __syncthreads();
    }
    if (t < NBUCKET) {
        int excl = s[t] - v;
        bbase[t] = excl;
        gcursor[t] = excl;
    }
    if (t == NBUCKET - 1) bbase[NBUCKET] = s[t];   // == NE
}

// coarse counting-sort into 391 bucket-contiguous regions.
// packed[pos] = ((rowlocal<<17)|col, w_bits); rowlocal<256, col<131072.
__global__ void bin_scatter(const int* __restrict__ rows, const int* __restrict__ cols,
                            const float* __restrict__ w,
                            int* __restrict__ gcursor, int2* __restrict__ packed) {
    __shared__ int spack[CHUNK];
    __shared__ float sw[CHUNK];
    __shared__ unsigned short sbuck[CHUNK];
    __shared__ int hist[NBUCKET];
    __shared__ int lbase[NBUCKET];
    int base = blockIdx.x * CHUNK;
    int n = min(CHUNK, NE - base);
    for (int t = threadIdx.x; t < NBUCKET; t += 256) hist[t] = 0;
    __syncthreads();
    for (int k = threadIdx.x; k < n; k += 256) {
        int e = base + k;
        int r = rows[e];
        int bk = r >> 8;
        spack[k] = ((r & 255) << 17) | cols[e];
        sw[k] = w[e];
        sbuck[k] = (unsigned short)bk;
        atomicAdd(&hist[bk], 1);
    }
    __syncthreads();
    for (int t = threadIdx.x; t < NBUCKET; t += 256) {
        int c = hist[t];
        lbase[t] = (c > 0) ? atomicAdd(&gcursor[t], c) : 0;
        hist[t] = 0;                                   // reuse as rank counter
    }
    __syncthreads();
    for (int k = threadIdx.x; k < n; k += 256) {
        int bk = sbuck[k];
        int rk = atomicAdd(&hist[bk], 1);
        packed[lbase[bk] + rk] = make_int2(spack[k], __float_as_int(sw[k]));
    }
}

// one block per (bucket, batch-half): LDS accumulate 256 rows x 8 batch,
// 64 edge-groups x 8 lanes, 2-way unroll. No global atomics.
__global__ void spmm_bucket(const int* __restrict__ bbase,
                            const int2* __restrict__ packed,
                            const float* __restrict__ h_in,
                            float* __restrict__ h_out) {
    __shared__ float acc[RPB * 8];
    int bucket = blockIdx.x >> 1;
    int bh = blockIdx.x & 1;
    int tid = threadIdx.x;                 // 512
    for (int k = tid; k < RPB * 8; k += 512) acc[k] = 0.f;
    __syncthreads();
    int j = tid & 7;
    int b = bh * 8 + j;                    // global batch index
    int g = tid >> 3;                      // 0..63
    int start = bbase[bucket];
    int end = bbase[bucket + 1];
    int i = start + g;
    for (; i + 64 < end; i += 128) {
        int2 e0 = packed[i];
        int2 e1 = packed[i + 64];
        float v0 = __int_as_float(e0.y) * h_in[(e0.x & 0x1FFFF) * NB + b];
        float v1 = __int_as_float(e1.y) * h_in[(e1.x & 0x1FFFF) * NB + b];
        atomicAdd(&acc[(e0.x >> 17) * 8 + j], v0);
        atomicAdd(&acc[(e1.x >> 17) * 8 + j], v1);
    }
    if (i < end) {
        int2 e0 = packed[i];
        float v0 = __int_as_float(e0.y) * h_in[(e0.x & 0x1FFFF) * NB + b];
        atomicAdd(&acc[(e0.x >> 17) * 8 + j], v0);
    }
    __syncthreads();
    int row0 = bucket * RPB;
    for (int k = tid; k < RPB * 8; k += 512) {
        int r = row0 + (k >> 3);
        if (r < NN) h_out[r * NB + bh * 8 + (k & 7)] = acc[k];
    }
}

// out[b] = sum_d dm_vals[d]*fc_w[d]*h[dm_cols[d]*16+b] + fc_b
__global__ void final_fc(const float* __restrict__ dmv,
                         const int* __restrict__ dmc,
                         const float* __restrict__ fcw,
                         const float* __restrict__ fcb,
                         const float* __restrict__ h,
                         float* __restrict__ out) {
    __shared__ float red[NB];
    int t = threadIdx.x;  // 512 threads, one per decision neuron
    if (t < NB) red[t] = 0.f;
    __syncthreads();
    float wd = dmv[t] * fcw[t];
    int c = dmc[t];
    for (int b = 0; b < NB; ++b) {
        float v = wd * h[c * NB + b];
        for (int off = 32; off; off >>= 1) v += __shfl_down(v, off);
        if ((t & 63) == 0) atomicAdd(&red[b], v);
    }
    __syncthreads();
    if (t < NB) out[t] = red[t] + fcb[0];
}

extern "C" void kernel_launch(void* const* d_in, const int* in_sizes, int n_in,
                              void* d_out, int out_size, void* d_ws, size_t ws_size,
                              hipStream_t stream) {
    const float* x   = (const float*)d_in[0];
    const float* tw  = (const float*)d_in[1];
    const float* tb  = (const float*)d_in[2];
    const float* ew  = (const float*)d_in[3];
    const float* dmv = (const float*)d_in[4];
    const float* fcw = (const float*)d_in[5];
    const float* fcb = (const float*)d_in[6];
    const int* ct  = (const int*)d_in[7];
    const int* er  = (const int*)d_in[8];
    const int* ec  = (const int*)d_in[9];
    const int* dmc = (const int*)d_in[10];
    float* out = (float*)d_out;

    char* ws = (char*)d_ws;
    float* h0      = (float*)ws;   ws += (size_t)NN * NB * 4;
    float* h1      = (float*)ws;   ws += (size_t)NN * NB * 4;
    int*   gcnt    = (int*)ws;     ws += (size_t)(NBUCKET + 8) * 4;
    int*   bbase   = (int*)ws;     ws += (size_t)(NBUCKET + 8) * 4;
    int*   gcursor = (int*)ws;     ws += (size_t)(NBUCKET + 8) * 4;
    ws = (char*)(((uintptr_t)ws + 15) & ~(uintptr_t)15);
    int2*  packed  = (int2*)ws;    // NE * 8B = 40MB

    int nchunks = (NE + CHUNK - 1) / CHUNK;   // 1221

    // --- coarse bucket sort (every call) ---
    hipMemsetAsync(gcnt, 0, (size_t)NBUCKET * 4, stream);
    bucket_count<<<nchunks, 256, 0, stream>>>(er, gcnt);
    bucket_scan<<<1, 512, 0, stream>>>(gcnt, bbase, gcursor);
    bin_scatter<<<nchunks, 256, 0, stream>>>(er, ec, ew, gcursor, packed);

    // --- h0 = per-type affine ---
    type_affine<<<(NN * NB + 255) / 256, 256, 0, stream>>>(x, tw, tb, ct, h0);

    // --- 4 x SpMM via LDS accumulation ---
    float* cur = h0;
    float* nxt = h1;
    for (int l = 0; l < NLAYER; ++l) {
        spmm_bucket<<<NBUCKET * 2, 512, 0, stream>>>(bbase, packed, cur, nxt);
        float* tmp = cur; cur = nxt; nxt = tmp;
    }

    final_fc<<<1, 512, 0, stream>>>(dmv, dmc, fcw, fcb, cur, out);
}

// Round 4
// 648.207 us; speedup vs baseline: 3.3993x; 3.3993x over previous
//
#include <hip/hip_runtime.h>

#define NN 100000
#define NE 5000000
#define NB 16
#define NDM 512

// v[dm_cols[d]] += dmv[d]*fc_w[d]   (512 entries, dup-safe)
__global__ void init_v(const float* __restrict__ dmv, const int* __restrict__ dmc,
                       const float* __restrict__ fcw, float* __restrict__ w) {
    int d = blockIdx.x * blockDim.x + threadIdx.x;
    if (d < NDM) atomicAdd(&w[dmc[d]], dmv[d] * fcw[d]);
}

// one transpose-SpMV hop: wn[ec[e]] += ew[e] * wc[er[e]]
// 4 edges per thread via 16B vector loads; skip atomics for zero contributions
// (hop 1 has only ~512 live sources -> ~25K atomics instead of 5M).
__global__ void spmv_t(const int4* __restrict__ er4, const int4* __restrict__ ec4,
                       const float4* __restrict__ ew4,
                       const float* __restrict__ wc, float* __restrict__ wn) {
    int i = blockIdx.x * blockDim.x + threadIdx.x;
    if (i >= NE / 4) return;
    int4 r = er4[i];
    float4 w = ew4[i];
    float v0 = w.x * wc[r.x];
    float v1 = w.y * wc[r.y];
    float v2 = w.z * wc[r.z];
    float v3 = w.w * wc[r.w];
    if (v0 != 0.f || v1 != 0.f || v2 != 0.f || v3 != 0.f) {
        int4 c = ec4[i];
        if (v0 != 0.f) atomicAdd(&wn[c.x], v0);
        if (v1 != 0.f) atomicAdd(&wn[c.y], v1);
        if (v2 != 0.f) atomicAdd(&wn[c.z], v2);
        if (v3 != 0.f) atomicAdd(&wn[c.w], v3);
    }
}

// out_acc[b] = sum_n u[n]*tw[ct[n]]*x[n*16+b]; out_acc[16] = sum_n u[n]*tb[ct[n]]
__global__ void final_dot(const float* __restrict__ x, const float* __restrict__ tw,
                          const float* __restrict__ tb, const int* __restrict__ ct,
                          const float* __restrict__ w,
                          float* __restrict__ acc_out) {
    __shared__ float sdata[4][16];
    __shared__ float sbias[4];
    int tid = threadIdx.x;          // 256
    int b = tid & 15;
    int g = tid >> 4;               // 16 neuron-groups per block
    float acc = 0.f, accb = 0.f;
    for (int n = blockIdx.x * 16 + g; n < NN; n += gridDim.x * 16) {
        float wn = w[n];
        int t = ct[n];
        acc = fmaf(wn * tw[t], x[n * NB + b], acc);   // 64B coalesced per group
        if (b == 0) accb = fmaf(wn, tb[t], accb);
    }
    acc += __shfl_xor(acc, 16);
    acc += __shfl_xor(acc, 32);
    accb += __shfl_xor(accb, 16);
    accb += __shfl_xor(accb, 32);
    int wv = tid >> 6;
    int lane = tid & 63;
    if (lane < 16) sdata[wv][lane] = acc;
    if (lane == 0) sbias[wv] = accb;
    __syncthreads();
    if (tid < 16)
        atomicAdd(&acc_out[tid], sdata[0][tid] + sdata[1][tid] + sdata[2][tid] + sdata[3][tid]);
    if (tid == 16)
        atomicAdd(&acc_out[16], sbias[0] + sbias[1] + sbias[2] + sbias[3]);
}

__global__ void finalize(const float* __restrict__ acc, const float* __restrict__ fcb,
                         float* __restrict__ out) {
    int b = threadIdx.x;
    if (b < NB) out[b] = acc[b] + acc[16] + fcb[0];
}

extern "C" void kernel_launch(void* const* d_in, const int* in_sizes, int n_in,
                              void* d_out, int out_size, void* d_ws, size_t ws_size,
                              hipStream_t stream) {
    const float* x   = (const float*)d_in[0];
    const float* tw  = (const float*)d_in[1];
    const float* tb  = (const float*)d_in[2];
    const float* ew  = (const float*)d_in[3];
    const float* dmv = (const float*)d_in[4];
    const float* fcw = (const float*)d_in[5];
    const float* fcb = (const float*)d_in[6];
    const int* ct  = (const int*)d_in[7];
    const int* er  = (const int*)d_in[8];
    const int* ec  = (const int*)d_in[9];
    const int* dmc = (const int*)d_in[10];
    float* out = (float*)d_out;

    char* ws = (char*)d_ws;
    float* wA  = (float*)ws;  ws += (size_t)NN * 4;
    float* wB  = (float*)ws;  ws += (size_t)NN * 4;
    float* acc = (float*)ws;  // 17 floats

    // u0 = v (decision-neuron weights scattered to neuron space)
    hipMemsetAsync(wA, 0, (size_t)NN * 4, stream);
    init_v<<<(NDM + 255) / 256, 256, 0, stream>>>(dmv, dmc, fcw, wA);

    // u = (A^T)^4 v : 4 scalar SpMV hops over the edge list
    float* cur = wA;
    float* nxt = wB;
    int blocks = (NE / 4 + 255) / 256;
    for (int l = 0; l < 4; ++l) {
        hipMemsetAsync(nxt, 0, (size_t)NN * 4, stream);
        spmv_t<<<blocks, 256, 0, stream>>>((const int4*)er, (const int4*)ec,
                                           (const float4*)ew, cur, nxt);
        float* tmp = cur; cur = nxt; nxt = tmp;
    }

    // out[b] = sum_n u[n]*(tw[ct[n]]*x[n,b] + tb[ct[n]]) + fcb
    hipMemsetAsync(acc, 0, 17 * 4, stream);
    final_dot<<<512, 256, 0, stream>>>(x, tw, tb, ct, cur, acc);
    finalize<<<1, 64, 0, stream>>>(acc, fcb, out);
}

// Round 5
// 263.471 us; speedup vs baseline: 8.3633x; 2.4603x over previous
//
#include <hip/hip_runtime.h>

#define NN 100000
#define NE 5000000
#define NB 16
#define NDM 512

#define RPB 256                              // rows per destination bucket
#define NBUCKET ((NN + RPB - 1) / RPB)       // 391
#define CHUNK 16384                          // edges per sort chunk
#define NCHUNK ((NE + CHUNK - 1) / CHUNK)    // 306
#define SUB 8                                // sub-blocks per bucket in hops

// v[dm_cols[d]] += dmv[d]*fc_w[d]   (512 entries, dup-safe)
__global__ void init_v(const float* __restrict__ dmv, const int* __restrict__ dmc,
                       const float* __restrict__ fcw, float* __restrict__ w) {
    int d = blockIdx.x * blockDim.x + threadIdx.x;
    if (d < NDM) atomicAdd(&w[dmc[d]], dmv[d] * fcw[d]);
}

// per-chunk LDS histogram of destination buckets
__global__ void bucket_count(const int* __restrict__ ec, int* __restrict__ gcnt) {
    __shared__ int hist[NBUCKET];
    for (int t = threadIdx.x; t < NBUCKET; t += 256) hist[t] = 0;
    __syncthreads();
    int base = blockIdx.x * CHUNK;
    int n = min(CHUNK, NE - base);
    for (int k = threadIdx.x; k < n; k += 256)
        atomicAdd(&hist[ec[base + k] >> 8], 1);
    __syncthreads();
    for (int t = threadIdx.x; t < NBUCKET; t += 256)
        if (hist[t]) atomicAdd(&gcnt[t], hist[t]);
}

// single-block exclusive scan of 391 bucket counts
__global__ void bucket_scan(const int* __restrict__ gcnt,
                            int* __restrict__ bbase, int* __restrict__ gcursor) {
    __shared__ int s[512];
    int t = threadIdx.x;
    int v = (t < NBUCKET) ? gcnt[t] : 0;
    s[t] = v;
    __syncthreads();
    for (int off = 1; off < 512; off <<= 1) {
        int u = (t >= off) ? s[t - off] : 0;
        __syncthreads();
        s[t] += u;
        __syncthreads();
    }
    if (t < NBUCKET) {
        int excl = s[t] - v;
        bbase[t] = excl;
        gcursor[t] = excl;
    }
    if (t == NBUCKET - 1) bbase[NBUCKET] = s[t];   // == NE
}

// two-pass chunked counting-sort by destination bucket.
// packed[pos] = ((dst&255)<<17 | src, w_bits)
__global__ void bin_scatter(const int* __restrict__ er, const int* __restrict__ ec,
                            const float* __restrict__ ew,
                            int* __restrict__ gcursor, int2* __restrict__ packed) {
    __shared__ int hist[NBUCKET];
    __shared__ int lbase[NBUCKET];
    int base = blockIdx.x * CHUNK;
    int n = min(CHUNK, NE - base);
    for (int t = threadIdx.x; t < NBUCKET; t += 256) hist[t] = 0;
    __syncthreads();
    for (int k = threadIdx.x; k < n; k += 256)
        atomicAdd(&hist[ec[base + k] >> 8], 1);
    __syncthreads();
    for (int t = threadIdx.x; t < NBUCKET; t += 256) {
        int c = hist[t];
        lbase[t] = c ? atomicAdd(&gcursor[t], c) : 0;
        hist[t] = 0;                                   // reuse as rank counter
    }
    __syncthreads();
    for (int k = threadIdx.x; k < n; k += 256) {
        int e = base + k;
        int d = ec[e];
        int bk = d >> 8;
        int rk = atomicAdd(&hist[bk], 1);
        packed[lbase[bk] + rk] =
            make_int2(((d & 255) << 17) | er[e], __float_as_int(ew[e]));
    }
}

// one hop u' = A^T u restricted to one destination bucket slice:
// LDS-accumulate 256 rows, flush with consecutive-lane atomics (line-merged).
__global__ void spmv_sorted(const int* __restrict__ bbase,
                            const int2* __restrict__ packed,
                            const float* __restrict__ wc, float* __restrict__ wn) {
    __shared__ float acc[RPB];
    int bucket = blockIdx.x >> 3;          // / SUB
    int sub = blockIdx.x & (SUB - 1);
    int t = threadIdx.x;                   // 256
    acc[t] = 0.f;
    __syncthreads();
    int s = bbase[bucket], e = bbase[bucket + 1];
    int cnt = e - s;
    int slice = (cnt + SUB - 1) >> 3;
    int mys = s + sub * slice;
    int mye = min(mys + slice, e);
    for (int i = mys + t; i < mye; i += 256) {
        int2 p = packed[i];
        float v = __int_as_float(p.y) * wc[p.x & 0x1FFFF];
        if (v != 0.f) atomicAdd(&acc[p.x >> 17], v);   // ds_add_f32
    }
    __syncthreads();
    float a = acc[t];
    int row = bucket * RPB + t;
    if (a != 0.f && row < NN) atomicAdd(&wn[row], a);
}

// acc_out[b] = sum_n u[n]*tw[ct[n]]*x[n*16+b]; acc_out[16] = sum_n u[n]*tb[ct[n]]
__global__ void final_dot(const float* __restrict__ x, const float* __restrict__ tw,
                          const float* __restrict__ tb, const int* __restrict__ ct,
                          const float* __restrict__ w,
                          float* __restrict__ acc_out) {
    __shared__ float sdata[4][16];
    __shared__ float sbias[4];
    int tid = threadIdx.x;          // 256
    int b = tid & 15;
    int g = tid >> 4;               // 16 neuron-groups per block
    float acc = 0.f, accb = 0.f;
    for (int n = blockIdx.x * 16 + g; n < NN; n += gridDim.x * 16) {
        float wn = w[n];
        int t = ct[n];
        acc = fmaf(wn * tw[t], x[n * NB + b], acc);
        if (b == 0) accb = fmaf(wn, tb[t], accb);
    }
    acc += __shfl_xor(acc, 16);
    acc += __shfl_xor(acc, 32);
    accb += __shfl_xor(accb, 16);
    accb += __shfl_xor(accb, 32);
    int wv = tid >> 6;
    int lane = tid & 63;
    if (lane < 16) sdata[wv][lane] = acc;
    if (lane == 0) sbias[wv] = accb;
    __syncthreads();
    if (tid < 16)
        atomicAdd(&acc_out[tid], sdata[0][tid] + sdata[1][tid] + sdata[2][tid] + sdata[3][tid]);
    if (tid == 16)
        atomicAdd(&acc_out[16], sbias[0] + sbias[1] + sbias[2] + sbias[3]);
}

__global__ void finalize(const float* __restrict__ acc, const float* __restrict__ fcb,
                         float* __restrict__ out) {
    int b = threadIdx.x;
    if (b < NB) out[b] = acc[b] + acc[16] + fcb[0];
}

extern "C" void kernel_launch(void* const* d_in, const int* in_sizes, int n_in,
                              void* d_out, int out_size, void* d_ws, size_t ws_size,
                              hipStream_t stream) {
    const float* x   = (const float*)d_in[0];
    const float* tw  = (const float*)d_in[1];
    const float* tb  = (const float*)d_in[2];
    const float* ew  = (const float*)d_in[3];
    const float* dmv = (const float*)d_in[4];
    const float* fcw = (const float*)d_in[5];
    const float* fcb = (const float*)d_in[6];
    const int* ct  = (const int*)d_in[7];
    const int* er  = (const int*)d_in[8];
    const int* ec  = (const int*)d_in[9];
    const int* dmc = (const int*)d_in[10];
    float* out = (float*)d_out;

    char* ws = (char*)d_ws;
    float* wA      = (float*)ws;  ws += (size_t)NN * 4;
    float* wB      = (float*)ws;  ws += (size_t)NN * 4;
    int*   gcnt    = (int*)ws;    ws += (size_t)(NBUCKET + 8) * 4;
    int*   bbase   = (int*)ws;    ws += (size_t)(NBUCKET + 8) * 4;
    int*   gcursor = (int*)ws;    ws += (size_t)(NBUCKET + 8) * 4;
    float* acc     = (float*)ws;  ws += 32 * 4;
    ws = (char*)(((uintptr_t)ws + 15) & ~(uintptr_t)15);
    int2*  packed  = (int2*)ws;   // NE * 8B = 40MB

    // --- destination-bucket counting sort (every call) ---
    hipMemsetAsync(gcnt, 0, (size_t)NBUCKET * 4, stream);
    bucket_count<<<NCHUNK, 256, 0, stream>>>(ec, gcnt);
    bucket_scan<<<1, 512, 0, stream>>>(gcnt, bbase, gcursor);
    bin_scatter<<<NCHUNK, 256, 0, stream>>>(er, ec, ew, gcursor, packed);

    // --- u0 = v ---
    hipMemsetAsync(wA, 0, (size_t)NN * 4, stream);
    init_v<<<(NDM + 255) / 256, 256, 0, stream>>>(dmv, dmc, fcw, wA);

    // --- u = (A^T)^4 v, LDS-accumulated hops ---
    float* cur = wA;
    float* nxt = wB;
    for (int l = 0; l < 4; ++l) {
        hipMemsetAsync(nxt, 0, (size_t)NN * 4, stream);
        spmv_sorted<<<NBUCKET * SUB, 256, 0, stream>>>(bbase, packed, cur, nxt);
        float* tmp = cur; cur = nxt; nxt = tmp;
    }

    // --- out[b] = sum_n u[n]*(tw[ct[n]]*x[n,b] + tb[ct[n]]) + fcb ---
    hipMemsetAsync(acc, 0, 17 * 4, stream);
    final_dot<<<512, 256, 0, stream>>>(x, tw, tb, ct, cur, acc);
    finalize<<<1, 64, 0, stream>>>(acc, fcb, out);
}

// Round 6
// 244.596 us; speedup vs baseline: 9.0086x; 1.0772x over previous
//
#include <hip/hip_runtime.h>

#define NN 100000
#define NE 5000000
#define NB 16
#define NDM 512

#define RPB 256                              // rows per destination bucket
#define NBUCKET ((NN + RPB - 1) / RPB)       // 391
#define CHUNK 4096                           // edges per sort chunk (divisible by 4)
#define NCHUNK ((NE + CHUNK - 1) / CHUNK)    // 1221 (last chunk 2880, still %4==0)
#define SUB 8                                // sub-blocks per bucket in hops

// v[dm_cols[d]] += dmv[d]*fc_w[d]
__global__ void init_v(const float* __restrict__ dmv, const int* __restrict__ dmc,
                       const float* __restrict__ fcw, float* __restrict__ w) {
    int d = blockIdx.x * blockDim.x + threadIdx.x;
    if (d < NDM) atomicAdd(&w[dmc[d]], dmv[d] * fcw[d]);
}

// per-chunk LDS histogram -> chunkhist row (coalesced) + global totals
__global__ void count_chunks(const int* __restrict__ ec,
                             int* __restrict__ chunkhist, int* __restrict__ gcnt) {
    __shared__ int hist[NBUCKET];
    for (int t = threadIdx.x; t < NBUCKET; t += 256) hist[t] = 0;
    __syncthreads();
    int base = blockIdx.x * CHUNK;
    int n = min(CHUNK, NE - base);
    const int4* ec4 = (const int4*)(ec + base);
    for (int k = threadIdx.x; k < (n >> 2); k += 256) {
        int4 c = ec4[k];
        atomicAdd(&hist[c.x >> 8], 1);
        atomicAdd(&hist[c.y >> 8], 1);
        atomicAdd(&hist[c.z >> 8], 1);
        atomicAdd(&hist[c.w >> 8], 1);
    }
    __syncthreads();
    int* row = chunkhist + (size_t)blockIdx.x * NBUCKET;
    for (int t = threadIdx.x; t < NBUCKET; t += 256) {
        int c = hist[t];
        row[t] = c;
        if (c) atomicAdd(&gcnt[t], c);
    }
}

// exclusive scan of 391 bucket totals -> bbase
__global__ void bucket_scan(const int* __restrict__ gcnt, int* __restrict__ bbase) {
    __shared__ int s[512];
    int t = threadIdx.x;
    int v = (t < NBUCKET) ? gcnt[t] : 0;
    s[t] = v;
    __syncthreads();
    for (int off = 1; off < 512; off <<= 1) {
        int u = (t >= off) ? s[t - off] : 0;
        __syncthreads();
        s[t] += u;
        __syncthreads();
    }
    if (t < NBUCKET) bbase[t] = s[t] - v;
    if (t == NBUCKET - 1) bbase[NBUCKET] = s[t];   // == NE
}

// per-bucket exclusive scan over chunks: chunkhist[c][t] <- bbase[t] + prefix
__global__ void colscan(int* __restrict__ chunkhist, const int* __restrict__ bbase) {
    __shared__ int s[256];
    int t = blockIdx.x;                  // bucket
    int carry = bbase[t];
    for (int tb = 0; tb < NCHUNK; tb += 256) {
        int c = tb + threadIdx.x;
        int v = (c < NCHUNK) ? chunkhist[(size_t)c * NBUCKET + t] : 0;
        s[threadIdx.x] = v;
        __syncthreads();
        for (int off = 1; off < 256; off <<= 1) {
            int u = (threadIdx.x >= off) ? s[threadIdx.x - off] : 0;
            __syncthreads();
            s[threadIdx.x] += u;
            __syncthreads();
        }
        if (c < NCHUNK) chunkhist[(size_t)c * NBUCKET + t] = carry + s[threadIdx.x] - v;
        int total = s[255];
        __syncthreads();                 // all read s[255] before next tile reuses s
        carry += total;
    }
}

// scatter: pos = cbase[chunk][bk] + LDS rank. No global cursor atomics.
// packed[pos] = ((dst&255)<<17 | src, w_bits)
__global__ void bin_scatter(const int* __restrict__ er, const int* __restrict__ ec,
                            const float* __restrict__ ew,
                            const int* __restrict__ cbase, int2* __restrict__ packed) {
    __shared__ int lbase[NBUCKET];
    __shared__ int lrank[NBUCKET];
    int base = blockIdx.x * CHUNK;
    int n = min(CHUNK, NE - base);
    const int* crow = cbase + (size_t)blockIdx.x * NBUCKET;
    for (int t = threadIdx.x; t < NBUCKET; t += 256) {
        lbase[t] = crow[t];
        lrank[t] = 0;
    }
    __syncthreads();
    const int4*   ec4 = (const int4*)(ec + base);
    const int4*   er4 = (const int4*)(er + base);
    const float4* ew4 = (const float4*)(ew + base);
    for (int k = threadIdx.x; k < (n >> 2); k += 256) {
        int4 c = ec4[k];
        int4 r = er4[k];
        float4 w = ew4[k];
        int bk, rk;
        bk = c.x >> 8; rk = atomicAdd(&lrank[bk], 1);
        packed[lbase[bk] + rk] = make_int2(((c.x & 255) << 17) | r.x, __float_as_int(w.x));
        bk = c.y >> 8; rk = atomicAdd(&lrank[bk], 1);
        packed[lbase[bk] + rk] = make_int2(((c.y & 255) << 17) | r.y, __float_as_int(w.y));
        bk = c.z >> 8; rk = atomicAdd(&lrank[bk], 1);
        packed[lbase[bk] + rk] = make_int2(((c.z & 255) << 17) | r.z, __float_as_int(w.z));
        bk = c.w >> 8; rk = atomicAdd(&lrank[bk], 1);
        packed[lbase[bk] + rk] = make_int2(((c.w & 255) << 17) | r.w, __float_as_int(w.w));
    }
}

// one hop u' = A^T u, one destination bucket slice per block:
// LDS-accumulate 256 rows, flush consecutive-lane global atomics.
__global__ void spmv_sorted(const int* __restrict__ bbase,
                            const int2* __restrict__ packed,
                            const float* __restrict__ wc, float* __restrict__ wn) {
    __shared__ float acc[RPB];
    int bucket = blockIdx.x >> 3;          // / SUB
    int sub = blockIdx.x & (SUB - 1);
    int t = threadIdx.x;                   // 256
    acc[t] = 0.f;
    __syncthreads();
    int s = bbase[bucket], e = bbase[bucket + 1];
    int cnt = e - s;
    int slice = (cnt + SUB - 1) >> 3;
    int mys = s + sub * slice;
    int mye = min(mys + slice, e);
    for (int i = mys + t; i < mye; i += 256) {
        int2 p = packed[i];
        float v = __int_as_float(p.y) * wc[p.x & 0x1FFFF];
        if (v != 0.f) atomicAdd(&acc[p.x >> 17], v);   // ds_add_f32
    }
    __syncthreads();
    float a = acc[t];
    int row = bucket * RPB + t;
    if (a != 0.f && row < NN) atomicAdd(&wn[row], a);
}

// acc_out[b] = sum_n u[n]*tw[ct[n]]*x[n*16+b]; acc_out[16] = sum_n u[n]*tb[ct[n]]
__global__ void final_dot(const float* __restrict__ x, const float* __restrict__ tw,
                          const float* __restrict__ tb, const int* __restrict__ ct,
                          const float* __restrict__ w,
                          float* __restrict__ acc_out) {
    __shared__ float sdata[4][16];
    __shared__ float sbias[4];
    int tid = threadIdx.x;          // 256
    int b = tid & 15;
    int g = tid >> 4;
    float acc = 0.f, accb = 0.f;
    for (int n = blockIdx.x * 16 + g; n < NN; n += gridDim.x * 16) {
        float wn = w[n];
        int t = ct[n];
        acc = fmaf(wn * tw[t], x[n * NB + b], acc);
        if (b == 0) accb = fmaf(wn, tb[t], accb);
    }
    acc += __shfl_xor(acc, 16);
    acc += __shfl_xor(acc, 32);
    accb += __shfl_xor(accb, 16);
    accb += __shfl_xor(accb, 32);
    int wv = tid >> 6;
    int lane = tid & 63;
    if (lane < 16) sdata[wv][lane] = acc;
    if (lane == 0) sbias[wv] = accb;
    __syncthreads();
    if (tid < 16)
        atomicAdd(&acc_out[tid], sdata[0][tid] + sdata[1][tid] + sdata[2][tid] + sdata[3][tid]);
    if (tid == 16)
        atomicAdd(&acc_out[16], sbias[0] + sbias[1] + sbias[2] + sbias[3]);
}

__global__ void finalize(const float* __restrict__ acc, const float* __restrict__ fcb,
                         float* __restrict__ out) {
    int b = threadIdx.x;
    if (b < NB) out[b] = acc[b] + acc[16] + fcb[0];
}

extern "C" void kernel_launch(void* const* d_in, const int* in_sizes, int n_in,
                              void* d_out, int out_size, void* d_ws, size_t ws_size,
                              hipStream_t stream) {
    const float* x   = (const float*)d_in[0];
    const float* tw  = (const float*)d_in[1];
    const float* tb  = (const float*)d_in[2];
    const float* ew  = (const float*)d_in[3];
    const float* dmv = (const float*)d_in[4];
    const float* fcw = (const float*)d_in[5];
    const float* fcb = (const float*)d_in[6];
    const int* ct  = (const int*)d_in[7];
    const int* er  = (const int*)d_in[8];
    const int* ec  = (const int*)d_in[9];
    const int* dmc = (const int*)d_in[10];
    float* out = (float*)d_out;

    char* ws = (char*)d_ws;
    float* wA        = (float*)ws;  ws += (size_t)NN * 4;
    float* wB        = (float*)ws;  ws += (size_t)NN * 4;
    int*   gcnt      = (int*)ws;    ws += (size_t)(NBUCKET + 8) * 4;
    int*   bbase     = (int*)ws;    ws += (size_t)(NBUCKET + 8) * 4;
    float* acc       = (float*)ws;  ws += 32 * 4;
    int*   chunkhist = (int*)ws;    ws += (size_t)NCHUNK * NBUCKET * 4;   // 1.9MB
    ws = (char*)(((uintptr_t)ws + 15) & ~(uintptr_t)15);
    int2*  packed    = (int2*)ws;   // NE * 8B = 40MB

    // --- destination-bucket counting sort, deterministic placement ---
    hipMemsetAsync(gcnt, 0, (size_t)NBUCKET * 4, stream);
    count_chunks<<<NCHUNK, 256, 0, stream>>>(ec, chunkhist, gcnt);
    bucket_scan<<<1, 512, 0, stream>>>(gcnt, bbase);
    colscan<<<NBUCKET, 256, 0, stream>>>(chunkhist, bbase);
    bin_scatter<<<NCHUNK, 256, 0, stream>>>(er, ec, ew, chunkhist, packed);

    // --- u0 = v ---
    hipMemsetAsync(wA, 0, (size_t)NN * 4, stream);
    init_v<<<(NDM + 255) / 256, 256, 0, stream>>>(dmv, dmc, fcw, wA);

    // --- u = (A^T)^4 v, LDS-accumulated hops ---
    float* cur = wA;
    float* nxt = wB;
    for (int l = 0; l < 4; ++l) {
        hipMemsetAsync(nxt, 0, (size_t)NN * 4, stream);
        spmv_sorted<<<NBUCKET * SUB, 256, 0, stream>>>(bbase, packed, cur, nxt);
        float* tmp = cur; cur = nxt; nxt = tmp;
    }

    // --- out[b] = sum_n u[n]*(tw[ct[n]]*x[n,b] + tb[ct[n]]) + fcb ---
    hipMemsetAsync(acc, 0, 17 * 4, stream);
    final_dot<<<512, 256, 0, stream>>>(x, tw, tb, ct, cur, acc);
    finalize<<<1, 64, 0, stream>>>(acc, fcb, out);
}

// Round 7
// 202.667 us; speedup vs baseline: 10.8724x; 1.2069x over previous
//
#include <hip/hip_runtime.h>

#define NN 100000
#define NE 5000000
#define NB 16
#define NDM 512

#define RPB 512                              // rows per destination bucket
#define NBUCKET ((NN + RPB - 1) / RPB)       // 196
#define CHUNK 8192                           // edges per sort chunk
#define NCHUNK ((NE + CHUNK - 1) / CHUNK)    // 611 (last chunk 2880, %4==0)
#define SUB 16                               // sub-blocks per bucket in hops

// v[dm_cols[d]] += dmv[d]*fc_w[d]
__global__ void init_v(const float* __restrict__ dmv, const int* __restrict__ dmc,
                       const float* __restrict__ fcw, float* __restrict__ w) {
    int d = blockIdx.x * blockDim.x + threadIdx.x;
    if (d < NDM) atomicAdd(&w[dmc[d]], dmv[d] * fcw[d]);
}

// per-chunk LDS histogram -> chunkhist row (coalesced) + global totals
__global__ void count_chunks(const int* __restrict__ ec,
                             int* __restrict__ chunkhist, int* __restrict__ gcnt) {
    __shared__ int hist[NBUCKET];
    for (int t = threadIdx.x; t < NBUCKET; t += 512) hist[t] = 0;
    __syncthreads();
    int base = blockIdx.x * CHUNK;
    int n = min(CHUNK, NE - base);
    const int4* ec4 = (const int4*)(ec + base);
    for (int k = threadIdx.x; k < (n >> 2); k += 512) {
        int4 c = ec4[k];
        atomicAdd(&hist[c.x >> 9], 1);
        atomicAdd(&hist[c.y >> 9], 1);
        atomicAdd(&hist[c.z >> 9], 1);
        atomicAdd(&hist[c.w >> 9], 1);
    }
    __syncthreads();
    int* row = chunkhist + (size_t)blockIdx.x * NBUCKET;
    for (int t = threadIdx.x; t < NBUCKET; t += 512) {
        int c = hist[t];
        row[t] = c;
        if (c) atomicAdd(&gcnt[t], c);
    }
}

// exclusive scan of 196 bucket totals -> bbase
__global__ void bucket_scan(const int* __restrict__ gcnt, int* __restrict__ bbase) {
    __shared__ int s[256];
    int t = threadIdx.x;
    int v = (t < NBUCKET) ? gcnt[t] : 0;
    s[t] = v;
    __syncthreads();
    for (int off = 1; off < 256; off <<= 1) {
        int u = (t >= off) ? s[t - off] : 0;
        __syncthreads();
        s[t] += u;
        __syncthreads();
    }
    if (t < NBUCKET) bbase[t] = s[t] - v;
    if (t == NBUCKET - 1) bbase[NBUCKET] = s[t];   // == NE
}

// per-bucket exclusive scan over chunks: chunkhist[c][t] <- bbase[t] + prefix
__global__ void colscan(int* __restrict__ chunkhist, const int* __restrict__ bbase) {
    __shared__ int s[256];
    int t = blockIdx.x;                  // bucket
    int carry = bbase[t];
    for (int tb = 0; tb < NCHUNK; tb += 256) {
        int c = tb + threadIdx.x;
        int v = (c < NCHUNK) ? chunkhist[(size_t)c * NBUCKET + t] : 0;
        s[threadIdx.x] = v;
        __syncthreads();
        for (int off = 1; off < 256; off <<= 1) {
            int u = (threadIdx.x >= off) ? s[threadIdx.x - off] : 0;
            __syncthreads();
            s[threadIdx.x] += u;
            __syncthreads();
        }
        if (c < NCHUNK) chunkhist[(size_t)c * NBUCKET + t] = carry + s[threadIdx.x] - v;
        int total = s[255];
        __syncthreads();
        carry += total;
    }
}

// scatter: pos = cbase[chunk][bk] + LDS rank. packed = ((dst&511)<<17 | src, w)
__global__ void bin_scatter(const int* __restrict__ er, const int* __restrict__ ec,
                            const float* __restrict__ ew,
                            const int* __restrict__ cbase, int2* __restrict__ packed) {
    __shared__ int lbase[NBUCKET];
    __shared__ int lrank[NBUCKET];
    int base = blockIdx.x * CHUNK;
    int n = min(CHUNK, NE - base);
    const int* crow = cbase + (size_t)blockIdx.x * NBUCKET;
    for (int t = threadIdx.x; t < NBUCKET; t += 512) {
        lbase[t] = crow[t];
        lrank[t] = 0;
    }
    __syncthreads();
    const int4*   ec4 = (const int4*)(ec + base);
    const int4*   er4 = (const int4*)(er + base);
    const float4* ew4 = (const float4*)(ew + base);
    for (int k = threadIdx.x; k < (n >> 2); k += 512) {
        int4 c = ec4[k];
        int4 r = er4[k];
        float4 w = ew4[k];
        int bk, rk;
        bk = c.x >> 9; rk = atomicAdd(&lrank[bk], 1);
        packed[lbase[bk] + rk] = make_int2(((c.x & 511) << 17) | r.x, __float_as_int(w.x));
        bk = c.y >> 9; rk = atomicAdd(&lrank[bk], 1);
        packed[lbase[bk] + rk] = make_int2(((c.y & 511) << 17) | r.y, __float_as_int(w.y));
        bk = c.z >> 9; rk = atomicAdd(&lrank[bk], 1);
        packed[lbase[bk] + rk] = make_int2(((c.z & 511) << 17) | r.z, __float_as_int(w.z));
        bk = c.w >> 9; rk = atomicAdd(&lrank[bk], 1);
        packed[lbase[bk] + rk] = make_int2(((c.w & 511) << 17) | r.w, __float_as_int(w.w));
    }
}

// one hop u' = A^T u, one destination-bucket slice per block:
// LDS-accumulate 512 rows, flush consecutive-lane global atomics.
__global__ void spmv_sorted(const int* __restrict__ bbase,
                            const int2* __restrict__ packed,
                            const float* __restrict__ wc, float* __restrict__ wn) {
    __shared__ float acc[RPB];
    int bucket = blockIdx.x >> 4;
    int sub = blockIdx.x & (SUB - 1);
    int t = threadIdx.x;                   // 256
    acc[t] = 0.f;
    acc[t + 256] = 0.f;
    __syncthreads();
    int s = bbase[bucket], e = bbase[bucket + 1];
    int cnt = e - s;
    int slice = (cnt + SUB - 1) >> 4;
    int mys = s + sub * slice;
    int mye = min(mys + slice, e);
    for (int i = mys + t; i < mye; i += 256) {
        int2 p = packed[i];
        float v = __int_as_float(p.y) * wc[p.x & 0x1FFFF];
        if (v != 0.f) atomicAdd(&acc[p.x >> 17], v);   // ds_add_f32, no return
    }
    __syncthreads();
    int row = bucket * RPB + t;
    float a = acc[t];
    if (a != 0.f && row < NN) atomicAdd(&wn[row], a);
    a = acc[t + 256];
    row += 256;
    if (a != 0.f && row < NN) atomicAdd(&wn[row], a);
}

// tiled final dot: 196 blocks x 512-row tiles.
// phase A: s[r] = u[n]*tw[ct[n]] (LDS), bias partial in regs
// phase B: acc[k] += s[r] * x[n][4*(tid&3)+k] via float4 loads
__global__ void final_dot(const float* __restrict__ x, const float* __restrict__ tw,
                          const float* __restrict__ tb, const int* __restrict__ ct,
                          const float* __restrict__ u,
                          float* __restrict__ acc_out) {
    __shared__ float s[512];
    __shared__ float sred[256][4];
    __shared__ float sbias[4];
    int tid = threadIdx.x;          // 256
    int base = blockIdx.x * 512;
    int nrows = min(512, NN - base);
    float accb = 0.f;
    for (int r = tid; r < nrows; r += 256) {
        int n = base + r;
        float un = u[n];
        int t = ct[n];
        s[r] = un * tw[t];
        accb = fmaf(un, tb[t], accb);
    }
    __syncthreads();
    float a0 = 0.f, a1 = 0.f, a2 = 0.f, a3 = 0.f;
    int j = (tid & 3) * 4;          // batch col base
    for (int r = tid >> 2; r < nrows; r += 64) {
        float4 xv = *(const float4*)&x[(size_t)(base + r) * NB + j];
        float sv = s[r];
        a0 = fmaf(sv, xv.x, a0);
        a1 = fmaf(sv, xv.y, a1);
        a2 = fmaf(sv, xv.z, a2);
        a3 = fmaf(sv, xv.w, a3);
    }
    sred[tid][0] = a0; sred[tid][1] = a1; sred[tid][2] = a2; sred[tid][3] = a3;
    // bias: wave reduce then cross-wave via LDS
    for (int off = 32; off; off >>= 1) accb += __shfl_down(accb, off);
    if ((tid & 63) == 0) sbias[tid >> 6] = accb;
    __syncthreads();
    if (tid < 16) {
        int q = tid >> 2, k = tid & 3;
        float sum = 0.f;
        for (int i = 0; i < 64; ++i) sum += sred[q + 4 * i][k];
        atomicAdd(&acc_out[tid], sum);
    }
    if (tid == 16)
        atomicAdd(&acc_out[16], sbias[0] + sbias[1] + sbias[2] + sbias[3]);
}

__global__ void finalize(const float* __restrict__ acc, const float* __restrict__ fcb,
                         float* __restrict__ out) {
    int b = threadIdx.x;
    if (b < NB) out[b] = acc[b] + acc[16] + fcb[0];
}

extern "C" void kernel_launch(void* const* d_in, const int* in_sizes, int n_in,
                              void* d_out, int out_size, void* d_ws, size_t ws_size,
                              hipStream_t stream) {
    const float* x   = (const float*)d_in[0];
    const float* tw  = (const float*)d_in[1];
    const float* tb  = (const float*)d_in[2];
    const float* ew  = (const float*)d_in[3];
    const float* dmv = (const float*)d_in[4];
    const float* fcw = (const float*)d_in[5];
    const float* fcb = (const float*)d_in[6];
    const int* ct  = (const int*)d_in[7];
    const int* er  = (const int*)d_in[8];
    const int* ec  = (const int*)d_in[9];
    const int* dmc = (const int*)d_in[10];
    float* out = (float*)d_out;

    char* ws = (char*)d_ws;
    float* wA        = (float*)ws;  ws += (size_t)NN * 4;
    float* wB        = (float*)ws;  ws += (size_t)NN * 4;
    int*   gcnt      = (int*)ws;    ws += (size_t)(NBUCKET + 8) * 4;
    int*   bbase     = (int*)ws;    ws += (size_t)(NBUCKET + 8) * 4;
    float* acc       = (float*)ws;  ws += 32 * 4;
    int*   chunkhist = (int*)ws;    ws += (size_t)NCHUNK * NBUCKET * 4;   // 479KB
    ws = (char*)(((uintptr_t)ws + 15) & ~(uintptr_t)15);
    int2*  packed    = (int2*)ws;   // NE * 8B = 40MB

    // --- destination-bucket counting sort, deterministic placement ---
    hipMemsetAsync(gcnt, 0, (size_t)NBUCKET * 4, stream);
    count_chunks<<<NCHUNK, 512, 0, stream>>>(ec, chunkhist, gcnt);
    bucket_scan<<<1, 256, 0, stream>>>(gcnt, bbase);
    colscan<<<NBUCKET, 256, 0, stream>>>(chunkhist, bbase);
    bin_scatter<<<NCHUNK, 512, 0, stream>>>(er, ec, ew, chunkhist, packed);

    // --- u0 = v ---
    hipMemsetAsync(wA, 0, (size_t)NN * 4, stream);
    init_v<<<(NDM + 255) / 256, 256, 0, stream>>>(dmv, dmc, fcw, wA);

    // --- u = (A^T)^4 v, LDS-accumulated hops ---
    float* cur = wA;
    float* nxt = wB;
    for (int l = 0; l < 4; ++l) {
        hipMemsetAsync(nxt, 0, (size_t)NN * 4, stream);
        spmv_sorted<<<NBUCKET * SUB, 256, 0, stream>>>(bbase, packed, cur, nxt);
        float* tmp = cur; cur = nxt; nxt = tmp;
    }

    // --- out[b] = sum_n u[n]*(tw[ct[n]]*x[n,b] + tb[ct[n]]) + fcb ---
    hipMemsetAsync(acc, 0, 17 * 4, stream);
    final_dot<<<NBUCKET, 256, 0, stream>>>(x, tw, tb, ct, cur, acc);
    finalize<<<1, 64, 0, stream>>>(acc, fcb, out);
}

// Round 8
// 188.802 us; speedup vs baseline: 11.6708x; 1.0734x over previous
//
#include <hip/hip_runtime.h>

#define NN 100000
#define NE 5000000
#define NB 16
#define NDM 512

#define RPB 512                              // rows per destination bucket
#define NBUCKET ((NN + RPB - 1) / RPB)       // 196
#define CHUNK 8192                           // edges per sort chunk
#define NCHUNK ((NE + CHUNK - 1) / CHUNK)    // 611 (last chunk 2880, %4==0)
#define SUB 8                                // sub-blocks per bucket in sorted hops
#define NWAVE 16                             // waves per 1024-thread block

// v[dm_cols[d]] += dmv[d]*fc_w[d]
__global__ void init_v(const float* __restrict__ dmv, const int* __restrict__ dmc,
                       const float* __restrict__ fcw, float* __restrict__ w) {
    int d = blockIdx.x * blockDim.x + threadIdx.x;
    if (d < NDM) atomicAdd(&w[dmc[d]], dmv[d] * fcw[d]);
}

// hop 1 on unsorted COO: u0 has <=512 nonzeros -> zero-skip on the gather side.
__global__ void spmv_first(const int4* __restrict__ er4, const int* __restrict__ ec,
                           const float* __restrict__ ew,
                           const float* __restrict__ wc, float* __restrict__ wn) {
    int i = blockIdx.x * blockDim.x + threadIdx.x;
    if (i >= NE / 4) return;
    int4 r = er4[i];
    float a0 = wc[r.x], a1 = wc[r.y], a2 = wc[r.z], a3 = wc[r.w];
    if (a0 != 0.f || a1 != 0.f || a2 != 0.f || a3 != 0.f) {
        int e = 4 * i;
        if (a0 != 0.f) atomicAdd(&wn[ec[e]],     ew[e]     * a0);
        if (a1 != 0.f) atomicAdd(&wn[ec[e + 1]], ew[e + 1] * a1);
        if (a2 != 0.f) atomicAdd(&wn[ec[e + 2]], ew[e + 2] * a2);
        if (a3 != 0.f) atomicAdd(&wn[ec[e + 3]], ew[e + 3] * a3);
    }
}

// per-chunk histogram (per-wave sub-hists) -> chunkhist row + global totals
__global__ void count_chunks(const int* __restrict__ ec,
                             int* __restrict__ chunkhist, int* __restrict__ gcnt) {
    __shared__ int hist[NWAVE][NBUCKET];
    int tid = threadIdx.x;                 // 1024
    int wv = tid >> 6;
    for (int t = tid; t < NWAVE * NBUCKET; t += 1024) hist[t / NBUCKET][t % NBUCKET] = 0;
    __syncthreads();
    int base = blockIdx.x * CHUNK;
    int n = min(CHUNK, NE - base);
    const int4* ec4 = (const int4*)(ec + base);
    for (int k = tid; k < (n >> 2); k += 1024) {
        int4 c = ec4[k];
        atomicAdd(&hist[wv][c.x >> 9], 1);
        atomicAdd(&hist[wv][c.y >> 9], 1);
        atomicAdd(&hist[wv][c.z >> 9], 1);
        atomicAdd(&hist[wv][c.w >> 9], 1);
    }
    __syncthreads();
    int* row = chunkhist + (size_t)blockIdx.x * NBUCKET;
    for (int t = tid; t < NBUCKET; t += 1024) {
        int c = 0;
        for (int w = 0; w < NWAVE; ++w) c += hist[w][t];
        row[t] = c;
        if (c) atomicAdd(&gcnt[t], c);
    }
}

// fused: per-bucket base (block-reduce over gcnt) + column scan over chunks
__global__ void scan_all(const int* __restrict__ gcnt,
                         int* __restrict__ chunkhist, int* __restrict__ bbase) {
    __shared__ int s[256];
    __shared__ int red[4];
    int b = blockIdx.x;                    // bucket
    int t = threadIdx.x;                   // 256
    int v = (t < b) ? gcnt[t] : 0;         // NBUCKET <= 256, single tile
    for (int off = 32; off; off >>= 1) v += __shfl_down(v, off);
    if ((t & 63) == 0) red[t >> 6] = v;
    __syncthreads();
    int base = red[0] + red[1] + red[2] + red[3];
    if (t == 0) {
        bbase[b] = base;
        if (b == NBUCKET - 1) bbase[NBUCKET] = base + gcnt[b];
    }
    int carry = base;
    for (int tb = 0; tb < NCHUNK; tb += 256) {
        int c = tb + t;
        int hv = (c < NCHUNK) ? chunkhist[(size_t)c * NBUCKET + b] : 0;
        s[t] = hv;
        __syncthreads();
        for (int off = 1; off < 256; off <<= 1) {
            int u = (t >= off) ? s[t - off] : 0;
            __syncthreads();
            s[t] += u;
            __syncthreads();
        }
        if (c < NCHUNK) chunkhist[(size_t)c * NBUCKET + b] = carry + s[t] - hv;
        int total = s[255];
        __syncthreads();
        carry += total;
    }
}

// scatter: pos = cbase[chunk][bk] + LDS rank. packed = ((dst&511)<<17 | src, w)
__global__ void bin_scatter(const int* __restrict__ er, const int* __restrict__ ec,
                            const float* __restrict__ ew,
                            const int* __restrict__ cbase, int2* __restrict__ packed) {
    __shared__ int lbase[NBUCKET];
    __shared__ int lrank[NBUCKET];
    int tid = threadIdx.x;                 // 1024
    int base = blockIdx.x * CHUNK;
    int n = min(CHUNK, NE - base);
    const int* crow = cbase + (size_t)blockIdx.x * NBUCKET;
    for (int t = tid; t < NBUCKET; t += 1024) {
        lbase[t] = crow[t];
        lrank[t] = 0;
    }
    __syncthreads();
    const int4*   ec4 = (const int4*)(ec + base);
    const int4*   er4 = (const int4*)(er + base);
    const float4* ew4 = (const float4*)(ew + base);
    for (int k = tid; k < (n >> 2); k += 1024) {
        int4 c = ec4[k];
        int4 r = er4[k];
        float4 w = ew4[k];
        int bk, rk;
        bk = c.x >> 9; rk = atomicAdd(&lrank[bk], 1);
        packed[lbase[bk] + rk] = make_int2(((c.x & 511) << 17) | r.x, __float_as_int(w.x));
        bk = c.y >> 9; rk = atomicAdd(&lrank[bk], 1);
        packed[lbase[bk] + rk] = make_int2(((c.y & 511) << 17) | r.y, __float_as_int(w.y));
        bk = c.z >> 9; rk = atomicAdd(&lrank[bk], 1);
        packed[lbase[bk] + rk] = make_int2(((c.z & 511) << 17) | r.z, __float_as_int(w.z));
        bk = c.w >> 9; rk = atomicAdd(&lrank[bk], 1);
        packed[lbase[bk] + rk] = make_int2(((c.w & 511) << 17) | r.w, __float_as_int(w.w));
    }
}

// sorted hop: LDS-accumulate 512 rows per bucket, ILP-4 packed reads,
// flush with consecutive-lane global atomics (line-merged).
__global__ void spmv_sorted(const int* __restrict__ bbase,
                            const int2* __restrict__ packed,
                            const float* __restrict__ wc, float* __restrict__ wn) {
    __shared__ float acc[RPB];
    int bucket = blockIdx.x >> 3;
    int sub = blockIdx.x & (SUB - 1);
    int t = threadIdx.x;                   // 256
    acc[t] = 0.f;
    acc[t + 256] = 0.f;
    __syncthreads();
    int s = bbase[bucket], e = bbase[bucket + 1];
    int cnt = e - s;
    int slice = (cnt + SUB - 1) >> 3;
    int mys = s + sub * slice;
    int mye = min(mys + slice, e);
    int i = mys + t;
    for (; i + 768 < mye; i += 1024) {
        int2 p0 = packed[i];
        int2 p1 = packed[i + 256];
        int2 p2 = packed[i + 512];
        int2 p3 = packed[i + 768];
        float v0 = __int_as_float(p0.y) * wc[p0.x & 0x1FFFF];
        float v1 = __int_as_float(p1.y) * wc[p1.x & 0x1FFFF];
        float v2 = __int_as_float(p2.y) * wc[p2.x & 0x1FFFF];
        float v3 = __int_as_float(p3.y) * wc[p3.x & 0x1FFFF];
        if (v0 != 0.f) atomicAdd(&acc[p0.x >> 17], v0);
        if (v1 != 0.f) atomicAdd(&acc[p1.x >> 17], v1);
        if (v2 != 0.f) atomicAdd(&acc[p2.x >> 17], v2);
        if (v3 != 0.f) atomicAdd(&acc[p3.x >> 17], v3);
    }
    for (; i < mye; i += 256) {
        int2 p = packed[i];
        float v = __int_as_float(p.y) * wc[p.x & 0x1FFFF];
        if (v != 0.f) atomicAdd(&acc[p.x >> 17], v);
    }
    __syncthreads();
    int row = bucket * RPB + t;
    float a = acc[t];
    if (a != 0.f && row < NN) atomicAdd(&wn[row], a);
    a = acc[t + 256];
    row += 256;
    if (a != 0.f && row < NN) atomicAdd(&wn[row], a);
}

// tiled final dot: 196 blocks x 512-row tiles
__global__ void final_dot(const float* __restrict__ x, const float* __restrict__ tw,
                          const float* __restrict__ tb, const int* __restrict__ ct,
                          const float* __restrict__ u,
                          float* __restrict__ acc_out) {
    __shared__ float s[512];
    __shared__ float sred[256][4];
    __shared__ float sbias[4];
    int tid = threadIdx.x;          // 256
    int base = blockIdx.x * 512;
    int nrows = min(512, NN - base);
    float accb = 0.f;
    for (int r = tid; r < nrows; r += 256) {
        int n = base + r;
        float un = u[n];
        int t = ct[n];
        s[r] = un * tw[t];
        accb = fmaf(un, tb[t], accb);
    }
    __syncthreads();
    float a0 = 0.f, a1 = 0.f, a2 = 0.f, a3 = 0.f;
    int j = (tid & 3) * 4;
    for (int r = tid >> 2; r < nrows; r += 64) {
        float4 xv = *(const float4*)&x[(size_t)(base + r) * NB + j];
        float sv = s[r];
        a0 = fmaf(sv, xv.x, a0);
        a1 = fmaf(sv, xv.y, a1);
        a2 = fmaf(sv, xv.z, a2);
        a3 = fmaf(sv, xv.w, a3);
    }
    sred[tid][0] = a0; sred[tid][1] = a1; sred[tid][2] = a2; sred[tid][3] = a3;
    for (int off = 32; off; off >>= 1) accb += __shfl_down(accb, off);
    if ((tid & 63) == 0) sbias[tid >> 6] = accb;
    __syncthreads();
    if (tid < 16) {
        int q = tid >> 2, k = tid & 3;
        float sum = 0.f;
        for (int i = 0; i < 64; ++i) sum += sred[q + 4 * i][k];
        atomicAdd(&acc_out[tid], sum);
    }
    if (tid == 16)
        atomicAdd(&acc_out[16], sbias[0] + sbias[1] + sbias[2] + sbias[3]);
}

__global__ void finalize(const float* __restrict__ acc, const float* __restrict__ fcb,
                         float* __restrict__ out) {
    int b = threadIdx.x;
    if (b < NB) out[b] = acc[b] + acc[16] + fcb[0];
}

extern "C" void kernel_launch(void* const* d_in, const int* in_sizes, int n_in,
                              void* d_out, int out_size, void* d_ws, size_t ws_size,
                              hipStream_t stream) {
    const float* x   = (const float*)d_in[0];
    const float* tw  = (const float*)d_in[1];
    const float* tb  = (const float*)d_in[2];
    const float* ew  = (const float*)d_in[3];
    const float* dmv = (const float*)d_in[4];
    const float* fcw = (const float*)d_in[5];
    const float* fcb = (const float*)d_in[6];
    const int* ct  = (const int*)d_in[7];
    const int* er  = (const int*)d_in[8];
    const int* ec  = (const int*)d_in[9];
    const int* dmc = (const int*)d_in[10];
    float* out = (float*)d_out;

    // workspace: [zero-region: gcnt(256) | u0..u4 (5*NN) | acc(32)] bbase chunkhist packed
    char* ws = (char*)d_ws;
    int*   gcnt = (int*)ws;
    float* u    = (float*)(ws + 256 * 4);          // u + k*NN, k=0..4
    float* acc  = u + 5 * (size_t)NN;
    size_t zero_bytes = (256 + 5 * (size_t)NN + 32) * 4;
    ws += zero_bytes;
    int* bbase = (int*)ws;          ws += (NBUCKET + 8) * 4;
    int* chunkhist = (int*)ws;      ws += (size_t)NCHUNK * NBUCKET * 4;   // 479KB
    ws = (char*)(((uintptr_t)ws + 15) & ~(uintptr_t)15);
    int2* packed = (int2*)ws;       // NE * 8B = 40MB

    // one memset zeroes gcnt, all hop buffers, and acc
    hipMemsetAsync(gcnt, 0, zero_bytes, stream);

    // u0 = v ; hop 1 directly on unsorted COO (source-sparse)
    init_v<<<(NDM + 255) / 256, 256, 0, stream>>>(dmv, dmc, fcw, u);
    spmv_first<<<(NE / 4 + 255) / 256, 256, 0, stream>>>((const int4*)er, ec, ew,
                                                         u, u + NN);

    // destination-bucket counting sort (deterministic placement)
    count_chunks<<<NCHUNK, 1024, 0, stream>>>(ec, chunkhist, gcnt);
    scan_all<<<NBUCKET, 256, 0, stream>>>(gcnt, chunkhist, bbase);
    bin_scatter<<<NCHUNK, 1024, 0, stream>>>(er, ec, ew, chunkhist, packed);

    // hops 2..4 on sorted packed edges
    for (int l = 1; l < 4; ++l) {
        spmv_sorted<<<NBUCKET * SUB, 256, 0, stream>>>(bbase, packed,
                                                       u + (size_t)l * NN,
                                                       u + (size_t)(l + 1) * NN);
    }

    // out[b] = sum_n u4[n]*(tw[ct[n]]*x[n,b] + tb[ct[n]]) + fcb
    final_dot<<<NBUCKET, 256, 0, stream>>>(x, tw, tb, ct, u + 4 * (size_t)NN, acc);
    finalize<<<1, 64, 0, stream>>>(acc, fcb, out);
}

// Round 9
// 170.524 us; speedup vs baseline: 12.9218x; 1.1072x over previous
//
#include <hip/hip_runtime.h>

#define NN 100000
#define NE 5000000
#define NB 16
#define NDM 512

#define RPB 1024                             // rows per destination bucket
#define NBUCKET 98                           // ceil(NN/RPB), 98*1024 = 100352
#define CAP 55296                            // per-bucket capacity (mean 51020 + 19 sigma)
#define CHUNK 8192                           // edges per scatter block
#define NCHUNK ((NE + CHUNK - 1) / CHUNK)    // 611 (last chunk 2880, %4==0)
#define SUB 16                               // sub-slices per bucket in hops
#define NWAVE 16                             // waves per 1024-thread block

// u0[dm_cols[d]] += dmv[d]*fc_w[d]; cursor[b] = b*CAP
__global__ void setup(const float* __restrict__ dmv, const int* __restrict__ dmc,
                      const float* __restrict__ fcw,
                      float* __restrict__ u0, int* __restrict__ cursor) {
    int t = threadIdx.x;                     // 512
    if (t < NDM) atomicAdd(&u0[dmc[t]], dmv[t] * fcw[t]);
    if (t < NBUCKET) cursor[t] = t * CAP;
}

// single-pass: histogram (LDS) -> reserve region (global cursor) -> scatter,
// with hop-1 (u1[ec] += ew*u0[er], source-sparse) fused into phase 2.
// packed[pos] = ((dst&1023)<<17 | src, w_bits)
__global__ void scatter_fused(const int* __restrict__ er, const int* __restrict__ ec,
                              const float* __restrict__ ew,
                              const float* __restrict__ u0, float* __restrict__ u1,
                              int* __restrict__ cursor, int2* __restrict__ packed) {
    __shared__ int hist[NWAVE][NBUCKET];
    __shared__ __align__(16) int sdst[CHUNK];   // staged ec values (32KB)
    __shared__ int lbase[NBUCKET];
    __shared__ int lrank[NBUCKET];
    int tid = threadIdx.x;                   // 1024
    int wv = tid >> 6;
    for (int k = tid; k < NWAVE * NBUCKET; k += 1024) hist[k / NBUCKET][k % NBUCKET] = 0;
    __syncthreads();
    int base = blockIdx.x * CHUNK;
    int n = min(CHUNK, NE - base);
    const int4* ec4 = (const int4*)(ec + base);
    // phase 1: stage ec + per-wave histogram
    for (int k = tid; k < (n >> 2); k += 1024) {
        int4 c = ec4[k];
        ((int4*)sdst)[k] = c;
        atomicAdd(&hist[wv][c.x >> 10], 1);
        atomicAdd(&hist[wv][c.y >> 10], 1);
        atomicAdd(&hist[wv][c.z >> 10], 1);
        atomicAdd(&hist[wv][c.w >> 10], 1);
    }
    __syncthreads();
    // reserve per-bucket space in one global atomic per (block,bucket)
    for (int b = tid; b < NBUCKET; b += 1024) {
        int c = 0;
        #pragma unroll
        for (int w = 0; w < NWAVE; ++w) c += hist[w][b];
        lbase[b] = c ? atomicAdd(&cursor[b], c) : 0;
        lrank[b] = 0;
    }
    __syncthreads();
    // phase 2: scatter + fused hop-1
    const int4*   er4 = (const int4*)(er + base);
    const float4* ew4 = (const float4*)(ew + base);
    for (int k = tid; k < (n >> 2); k += 1024) {
        int4 r = er4[k];
        float4 w = ew4[k];
        int k4 = 4 * k;
        int d, bk, rk;
        float a;
        d = sdst[k4];     bk = d >> 10; rk = atomicAdd(&lrank[bk], 1);
        packed[lbase[bk] + rk] = make_int2(((d & 1023) << 17) | r.x, __float_as_int(w.x));
        a = u0[r.x]; if (a != 0.f) atomicAdd(&u1[d], w.x * a);
        d = sdst[k4 + 1]; bk = d >> 10; rk = atomicAdd(&lrank[bk], 1);
        packed[lbase[bk] + rk] = make_int2(((d & 1023) << 17) | r.y, __float_as_int(w.y));
        a = u0[r.y]; if (a != 0.f) atomicAdd(&u1[d], w.y * a);
        d = sdst[k4 + 2]; bk = d >> 10; rk = atomicAdd(&lrank[bk], 1);
        packed[lbase[bk] + rk] = make_int2(((d & 1023) << 17) | r.z, __float_as_int(w.z));
        a = u0[r.z]; if (a != 0.f) atomicAdd(&u1[d], w.z * a);
        d = sdst[k4 + 3]; bk = d >> 10; rk = atomicAdd(&lrank[bk], 1);
        packed[lbase[bk] + rk] = make_int2(((d & 1023) << 17) | r.w, __float_as_int(w.w));
        a = u0[r.w]; if (a != 0.f) atomicAdd(&u1[d], w.w * a);
    }
}

// sorted hop: LDS-accumulate 1024 rows per bucket, ILP-4 packed reads,
// flush with consecutive-lane global atomics (line-merged).
__global__ void spmv_sorted(const int* __restrict__ cursor,
                            const int2* __restrict__ packed,
                            const float* __restrict__ wc, float* __restrict__ wn) {
    __shared__ float acc[RPB];
    int bucket = blockIdx.x >> 4;            // / SUB
    int sub = blockIdx.x & (SUB - 1);
    int t = threadIdx.x;                     // 256
    #pragma unroll
    for (int k = 0; k < 4; ++k) acc[t + 256 * k] = 0.f;
    __syncthreads();
    int s = bucket * CAP;
    int e = cursor[bucket];                  // region end after reservation
    int cnt = e - s;
    int slice = (cnt + SUB - 1) >> 4;
    int mys = s + sub * slice;
    int mye = min(mys + slice, e);
    int i = mys + t;
    for (; i + 768 < mye; i += 1024) {
        int2 p0 = packed[i];
        int2 p1 = packed[i + 256];
        int2 p2 = packed[i + 512];
        int2 p3 = packed[i + 768];
        float v0 = __int_as_float(p0.y) * wc[p0.x & 0x1FFFF];
        float v1 = __int_as_float(p1.y) * wc[p1.x & 0x1FFFF];
        float v2 = __int_as_float(p2.y) * wc[p2.x & 0x1FFFF];
        float v3 = __int_as_float(p3.y) * wc[p3.x & 0x1FFFF];
        if (v0 != 0.f) atomicAdd(&acc[p0.x >> 17], v0);
        if (v1 != 0.f) atomicAdd(&acc[p1.x >> 17], v1);
        if (v2 != 0.f) atomicAdd(&acc[p2.x >> 17], v2);
        if (v3 != 0.f) atomicAdd(&acc[p3.x >> 17], v3);
    }
    for (; i < mye; i += 256) {
        int2 p = packed[i];
        float v = __int_as_float(p.y) * wc[p.x & 0x1FFFF];
        if (v != 0.f) atomicAdd(&acc[p.x >> 17], v);
    }
    __syncthreads();
    #pragma unroll
    for (int k = 0; k < 4; ++k) {
        int row = bucket * RPB + t + 256 * k;
        float a = acc[t + 256 * k];
        if (a != 0.f && row < NN) atomicAdd(&wn[row], a);
    }
}

// tiled final dot: 196 blocks x 512-row tiles
__global__ void final_dot(const float* __restrict__ x, const float* __restrict__ tw,
                          const float* __restrict__ tb, const int* __restrict__ ct,
                          const float* __restrict__ u,
                          float* __restrict__ acc_out) {
    __shared__ float s[512];
    __shared__ float sred[256][4];
    __shared__ float sbias[4];
    int tid = threadIdx.x;          // 256
    int base = blockIdx.x * 512;
    int nrows = min(512, NN - base);
    float accb = 0.f;
    for (int r = tid; r < nrows; r += 256) {
        int n = base + r;
        float un = u[n];
        int t = ct[n];
        s[r] = un * tw[t];
        accb = fmaf(un, tb[t], accb);
    }
    __syncthreads();
    float a0 = 0.f, a1 = 0.f, a2 = 0.f, a3 = 0.f;
    int j = (tid & 3) * 4;
    for (int r = tid >> 2; r < nrows; r += 64) {
        float4 xv = *(const float4*)&x[(size_t)(base + r) * NB + j];
        float sv = s[r];
        a0 = fmaf(sv, xv.x, a0);
        a1 = fmaf(sv, xv.y, a1);
        a2 = fmaf(sv, xv.z, a2);
        a3 = fmaf(sv, xv.w, a3);
    }
    sred[tid][0] = a0; sred[tid][1] = a1; sred[tid][2] = a2; sred[tid][3] = a3;
    for (int off = 32; off; off >>= 1) accb += __shfl_down(accb, off);
    if ((tid & 63) == 0) sbias[tid >> 6] = accb;
    __syncthreads();
    if (tid < 16) {
        int q = tid >> 2, k = tid & 3;
        float sum = 0.f;
        for (int i = 0; i < 64; ++i) sum += sred[q + 4 * i][k];
        atomicAdd(&acc_out[tid], sum);
    }
    if (tid == 16)
        atomicAdd(&acc_out[16], sbias[0] + sbias[1] + sbias[2] + sbias[3]);
}

__global__ void finalize(const float* __restrict__ acc, const float* __restrict__ fcb,
                         float* __restrict__ out) {
    int b = threadIdx.x;
    if (b < NB) out[b] = acc[b] + acc[16] + fcb[0];
}

extern "C" void kernel_launch(void* const* d_in, const int* in_sizes, int n_in,
                              void* d_out, int out_size, void* d_ws, size_t ws_size,
                              hipStream_t stream) {
    const float* x   = (const float*)d_in[0];
    const float* tw  = (const float*)d_in[1];
    const float* tb  = (const float*)d_in[2];
    const float* ew  = (const float*)d_in[3];
    const float* dmv = (const float*)d_in[4];
    const float* fcw = (const float*)d_in[5];
    const float* fcb = (const float*)d_in[6];
    const int* ct  = (const int*)d_in[7];
    const int* er  = (const int*)d_in[8];
    const int* ec  = (const int*)d_in[9];
    const int* dmc = (const int*)d_in[10];
    float* out = (float*)d_out;

    // ws: [zero-region: u0..u4 (5*NN) | acc(32)] cursor(128) packed(98*CAP*8 = 43.4MB)
    char* ws = (char*)d_ws;
    float* u   = (float*)ws;                       // u + k*NN, k=0..4
    float* acc = u + 5 * (size_t)NN;
    size_t zero_bytes = (5 * (size_t)NN + 32) * 4;
    ws += zero_bytes;
    int* cursor = (int*)ws;         ws += 128 * 4;
    ws = (char*)(((uintptr_t)ws + 15) & ~(uintptr_t)15);
    int2* packed = (int2*)ws;       // NBUCKET * CAP * 8B

    // zero all hop buffers + acc (cursor is set by setup, not zeroed)
    hipMemsetAsync(u, 0, zero_bytes, stream);

    // u0 = v; cursor[b] = b*CAP
    setup<<<1, 512, 0, stream>>>(dmv, dmc, fcw, u, cursor);

    // one pass over edges: bucket-sort into packed + fused hop 1 (u0 -> u1)
    scatter_fused<<<NCHUNK, 1024, 0, stream>>>(er, ec, ew, u, u + NN, cursor, packed);

    // hops 2..4 on sorted packed edges
    for (int l = 1; l < 4; ++l) {
        spmv_sorted<<<NBUCKET * SUB, 256, 0, stream>>>(cursor, packed,
                                                       u + (size_t)l * NN,
                                                       u + (size_t)(l + 1) * NN);
    }

    // out[b] = sum_n u4[n]*(tw[ct[n]]*x[n,b] + tb[ct[n]]) + fcb
    final_dot<<<(NN + 511) / 512, 256, 0, stream>>>(x, tw, tb, ct, u + 4 * (size_t)NN, acc);
    finalize<<<1, 64, 0, stream>>>(acc, fcb, out);
}